// Round 2
// baseline (141.009 us; speedup 1.0000x reference)
//
#include <hip/hip_runtime.h>

// YOLO layer decode: input (B=16, A*(C+5)=255, H=76, W=76) fp32, anchors (3,2) fp32.
// Output boxes (B, A, H, W, 7): [xs, ys, ws, hs, conf, cls_prob, cls_id].
//
// R5b: retry of R5 (previous round's bench was an infra failure — container
// acquire failed twice; no kernel verdict). Kernel unchanged.
//
// R5: float4 vectorization. rocprof showed the 138us timed region is dominated
// by ~110us of harness re-poison fills (55us fillBuffer dispatches top the
// profile); the kernel itself is ~27us vs a ~16us traffic floor (94MB in +
// 7.8MB out @ 6.3TB/s). Remaining kernel inefficiency = 4B/lane dword loads.
// Now each lane handles 4 consecutive positions via float4 (PLANE=5776 is
// divisible by 4, so a float4 never crosses a channel plane), with ONLINE
// softmax (running m/s/id) so we never hold 20x4 logits in registers.
// Class-split across 4 waves retained (wave w owns classes [20w,20w+20)),
// merged via LDS with rescale S = sum s_w * exp(m_w - M).

#define B_  16
#define A_  3
#define C_  80
#define H_  76
#define W_  76
#define PLANE (H_ * W_)   // 5776
#define CPW  20           // classes per wave (4 waves * 20 = 80)
#define PPL  4            // positions per lane (float4)
#define PPB  256          // positions per block (64 lanes * PPL)

__device__ __forceinline__ float fast_exp(float x) {
    return __builtin_amdgcn_exp2f(x * 1.44269504088896340736f);  // v_exp_f32 = 2^x
}

__device__ __forceinline__ float fast_rcp(float x) {
    return __builtin_amdgcn_rcpf(x);
}

__device__ __forceinline__ float sigmoidf(float x) {
    return fast_rcp(1.0f + fast_exp(-x));
}

__global__ __launch_bounds__(256, 4) void yolo_kernel(const float* __restrict__ in,
                                                      const float* __restrict__ anchors,
                                                      float* __restrict__ out) {
    const int tid  = threadIdx.x;
    const int lane = tid & 63;
    const int wid  = tid >> 6;          // 0..3: which class group
    const int a = blockIdx.y;
    const int b = blockIdx.z;
    const int pos_base = blockIdx.x * PPB;
    const int p0  = pos_base + lane * PPL;
    const int p0c = (p0 <= PLANE - PPL) ? p0 : (PLANE - PPL);  // clamp, stays 16B-aligned

    const float* base = in + (size_t)((b * A_ + a) * (C_ + 5)) * PLANE + p0c;
    const float* cb   = base + (size_t)(5 + wid * CPW) * PLANE;

    // ---- online softmax over this wave's 20 classes, 4 positions per lane ----
    // 20 independent global_load_dwordx4 per lane (1KB per wave-instruction).
    float m[PPL], s[PPL];
    int   id[PPL];
    {
        const float4 v0 = *(const float4*)cb;   // j = 0
        m[0] = v0.x; m[1] = v0.y; m[2] = v0.z; m[3] = v0.w;
        #pragma unroll
        for (int k = 0; k < PPL; ++k) { s[k] = 1.0f; id[k] = 0; }
    }
    #pragma unroll
    for (int j = 1; j < CPW; ++j) {
        const float4 vj = *(const float4*)(cb + (size_t)j * PLANE);
        const float lv[PPL] = {vj.x, vj.y, vj.z, vj.w};
        #pragma unroll
        for (int k = 0; k < PPL; ++k) {
            const float mn = fmaxf(m[k], lv[k]);
            // not-new-max: exp(m-mn)=1 -> s += exp(lv-mn); new-max: s*exp(m-mn)+1
            s[k] = s[k] * fast_exp(m[k] - mn) + fast_exp(lv[k] - mn);
            if (lv[k] > m[k]) id[k] = j;     // strict > before m update => first occurrence
            m[k] = mn;
        }
    }

    // ---- box channels: wave 0 only (wave-uniform branch), float4 loads ----
    float tb[5][PPL];
    if (wid == 0) {
        #pragma unroll
        for (int c = 0; c < 5; ++c) {
            const float4 v = *(const float4*)(base + (size_t)c * PLANE);
            tb[c][0] = v.x; tb[c][1] = v.y; tb[c][2] = v.z; tb[c][3] = v.w;
        }
    }

    __shared__ __align__(16) float sm[4][64][PPL];
    __shared__ __align__(16) float ss[4][64][PPL];
    __shared__ __align__(16) int   sd[4][64][PPL];
    __shared__ __align__(16) float res[PPB * 7];

    // contiguous b128 LDS writes (conflict-free)
    *(float4*)sm[wid][lane] = make_float4(m[0], m[1], m[2], m[3]);
    *(float4*)ss[wid][lane] = make_float4(s[0], s[1], s[2], s[3]);
    *(int4*)  sd[wid][lane] = make_int4(id[0] + wid * CPW, id[1] + wid * CPW,
                                        id[2] + wid * CPW, id[3] + wid * CPW);
    __syncthreads();

    if (wid == 0) {
        const float aw = anchors[2 * a + 0] * (1.0f / (float)W_);
        const float ah = anchors[2 * a + 1] * (1.0f / (float)H_);
        #pragma unroll
        for (int k = 0; k < PPL; ++k) {
            // combine in increasing wid order, strict > => global first-occurrence argmax
            float M  = sm[0][lane][k];
            int   ID = sd[0][lane][k];
            #pragma unroll
            for (int w = 1; w < 4; ++w) {
                const float mw = sm[w][lane][k];
                if (mw > M) { M = mw; ID = sd[w][lane][k]; }
            }
            float S = 0.0f;
            #pragma unroll
            for (int w = 0; w < 4; ++w) S += ss[w][lane][k] * fast_exp(sm[w][lane][k] - M);

            const int p = p0c + k;
            const int x = p % W_;
            const int y = p / W_;
            float* r = &res[(lane * PPL + k) * 7];
            r[0] = (sigmoidf(tb[0][k]) + (float)x) * (1.0f / (float)W_);
            r[1] = (sigmoidf(tb[1][k]) + (float)y) * (1.0f / (float)H_);
            r[2] = fast_exp(tb[2][k]) * aw;
            r[3] = fast_exp(tb[3][k]) * ah;
            r[4] = sigmoidf(tb[4][k]);
            r[5] = fast_rcp(S);     // max softmax prob = exp(M-M)/S = 1/S
            r[6] = (float)ID;
        }
    }
    __syncthreads();

    // ---- coalesced float4 store: 1792 contiguous floats per full block ----
    const int nvalid = (PLANE - pos_base < PPB) ? (PLANE - pos_base) : PPB;  // 256 or 144
    const int n4 = nvalid * 7 / 4;            // 448 (full) or 252 (tail) — both exact
    const size_t obase = (size_t)((b * A_ + a) * PLANE + pos_base) * 7;      // 16B-aligned
    float4* out4 = (float4*)(out + obase);
    const float4* res4 = (const float4*)res;
    #pragma unroll
    for (int t = 0; t < 2; ++t) {
        const int idx = tid + t * 256;
        if (idx < n4) out4[idx] = res4[idx];
    }
}

extern "C" void kernel_launch(void* const* d_in, const int* in_sizes, int n_in,
                              void* d_out, int out_size, void* d_ws, size_t ws_size,
                              hipStream_t stream) {
    const float* in      = (const float*)d_in[0];
    const float* anchors = (const float*)d_in[1];
    float* out           = (float*)d_out;

    dim3 grid((PLANE + PPB - 1) / PPB, A_, B_);   // (23, 3, 16) = 1104 blocks, 4 waves each
    dim3 block(256, 1, 1);
    yolo_kernel<<<grid, block, 0, stream>>>(in, anchors, out);
}